// Round 1
// baseline (6543.457 us; speedup 1.0000x reference)
//
#include <hip/hip_runtime.h>
#include <math.h>

// Problem constants
#define HD    1024      // hidden size
#define SEQL  512       // sequence length
#define NLAB  122       // labels
#define NWG   128       // workgroups in persistent recurrent kernel
#define JPW   8         // h-columns (j) per workgroup  (NWG*JPW == HD)

// Workspace layout (bytes). Total needed ≈ 27.6 MB.
#define OFF_HBUF  ((size_t)0)          // h double buffer: 2*1024 fp32          = 8192 B
#define OFF_FLAGS ((size_t)8192)       // flags: 512 * 128 u32                  = 262144 B
#define OFF_GATES ((size_t)270336)     // gates_x: 512*4096 fp32                = 8388608 B
#define OFF_WR    ((size_t)8658944)    // W_r2: 4096*1024 fp32 (swizzled)       = 16777216 B
#define OFF_HALL  ((size_t)25436160)   // h_all: 512*1024 fp32                  = 2097152 B
// end = 27533312

// ---------------------------------------------------------------------------
// Prep: W_r2[g][kq][row_local][kk] = W_ih[R][4096+k] + W_hh[R][k]
//   g in [0,128), kq in [0,32), row_local = gate*8+jj in [0,32), kk in [0,32)
//   R = gate*1024 + g*8 + jj,  k = kq*32 + kk
// 4096 blocks x 256 threads, one float4 each.
__global__ __launch_bounds__(256) void prep_wr(const float* __restrict__ W_ih,
                                               const float* __restrict__ W_hh,
                                               float* __restrict__ W_r2) {
    int idx4 = blockIdx.x * 256 + threadIdx.x;   // float4 index
    int e = idx4 * 4;                            // element index, < 4194304
    int g   = e >> 15;
    int rem = e & 32767;
    int kq  = rem >> 10;
    int row = (rem >> 5) & 31;
    int kk  = e & 31;
    int R = ((row >> 3) << 10) + (g << 3) + (row & 7);
    int k = (kq << 5) + kk;
    float4 wa = *(const float4*)(W_ih + (size_t)R * 5120 + 4096 + k);
    float4 wb = *(const float4*)(W_hh + (size_t)R * 1024 + k);
    float4 o;
    o.x = wa.x + wb.x; o.y = wa.y + wb.y; o.z = wa.z + wb.z; o.w = wa.w + wb.w;
    *(float4*)(W_r2 + e) = o;
}

// ---------------------------------------------------------------------------
// gates_x[t][r] = b_ih[r] + b_hh[r] + sum_{k<4096} feats[t][k] * W_ih[r][k]
// feats[t] = concat(x[t] (2048), hi[t] (2048)).
// 64x64 tile per WG of 256 threads, BK=16, fp32 VALU GEMM.
__global__ __launch_bounds__(256) void gates_gemm(const float* __restrict__ x,
                                                  const float* __restrict__ hi,
                                                  const float* __restrict__ W_ih,
                                                  const float* __restrict__ b_ih,
                                                  const float* __restrict__ b_hh,
                                                  float* __restrict__ gates_x) {
    __shared__ float As[16][68];   // [k][t], padded: stride 68 keeps 16B align + bank spread
    __shared__ float Bs[16][68];   // [k][r]
    const int tid = threadIdx.x;
    const int r0 = blockIdx.x * 64;
    const int t0 = blockIdx.y * 64;
    const int tx = tid & 15, ty = tid >> 4;
    const int l   = tid & 63;    // row-in-tile for staging
    const int kq4 = tid >> 6;    // 0..3 -> which float4 of the BK=16 slab

    float acc[4][4] = {};
    for (int kb = 0; kb < 4096; kb += 16) {
        int k = kb + kq4 * 4;
        const float* asrc = (k < 2048) ? (x  + (size_t)(t0 + l) * 2048 + k)
                                       : (hi + (size_t)(t0 + l) * 2048 + (k - 2048));
        float4 a4 = *(const float4*)asrc;
        float4 b4 = *(const float4*)(W_ih + (size_t)(r0 + l) * 5120 + k);
        __syncthreads();   // previous iteration's reads done before overwrite
        As[kq4 * 4 + 0][l] = a4.x; As[kq4 * 4 + 1][l] = a4.y;
        As[kq4 * 4 + 2][l] = a4.z; As[kq4 * 4 + 3][l] = a4.w;
        Bs[kq4 * 4 + 0][l] = b4.x; Bs[kq4 * 4 + 1][l] = b4.y;
        Bs[kq4 * 4 + 2][l] = b4.z; Bs[kq4 * 4 + 3][l] = b4.w;
        __syncthreads();
        #pragma unroll
        for (int kk = 0; kk < 16; ++kk) {
            float4 av = *(const float4*)&As[kk][ty * 4];
            float4 bv = *(const float4*)&Bs[kk][tx * 4];
            float a_[4] = {av.x, av.y, av.z, av.w};
            float b_[4] = {bv.x, bv.y, bv.z, bv.w};
            #pragma unroll
            for (int i = 0; i < 4; ++i)
                #pragma unroll
                for (int j = 0; j < 4; ++j)
                    acc[i][j] += a_[i] * b_[j];
        }
    }
    int r = r0 + tx * 4;
    float bias[4];
    #pragma unroll
    for (int j = 0; j < 4; ++j) bias[j] = b_ih[r + j] + b_hh[r + j];
    #pragma unroll
    for (int i = 0; i < 4; ++i) {
        float4 o;
        o.x = acc[i][0] + bias[0]; o.y = acc[i][1] + bias[1];
        o.z = acc[i][2] + bias[2]; o.w = acc[i][3] + bias[3];
        *(float4*)(gates_x + (size_t)(t0 + ty * 4 + i) * 4096 + r) = o;
    }
}

// ---------------------------------------------------------------------------
// Persistent recurrent kernel. NWG workgroups x 256 threads, all co-resident.
// WG g owns j in [g*8, g*8+8): 32 gate rows (i,f,g,o x 8).
// Thread (kq = tid>>3 in [0,32), rg = tid&7): rows rg*4..rg*4+3, k-slice kq*32..+32.
// Cross-WG h exchange: double-buffered h_buf in global, agent-scope atomics;
// per-WG per-step release flag, 128 spinner threads (one flag each).
__global__ __launch_bounds__(256) void lstm_rec(const float* __restrict__ gates_x,
                                                const float* __restrict__ W_r2,
                                                float* __restrict__ h_all,
                                                float* h_buf,
                                                unsigned* flags) {
    const int g   = blockIdx.x;
    const int tid = threadIdx.x;
    const int kq  = tid >> 3;
    const int rg  = tid & 7;
    __shared__ float4 h_s[256];
    __shared__ float  partial[32][33];
    __shared__ float  gv_s[32];
    __shared__ float  c_s[JPW];
    if (tid < JPW) c_s[tid] = 0.f;

    const float4* Wp = ((const float4*)W_r2) + ((size_t)(g * 32 + kq) * 32 + rg * 4) * 8;

    for (int t = 0; t < SEQL; ++t) {
        // prefetch this step's gates_x early (independent of h)
        float gx = 0.f;
        if (tid < 32)
            gx = gates_x[(size_t)t * 4096 + ((tid >> 3) << 10) + (g << 3) + (tid & 7)];

        if (t > 0 && tid < NWG) {
            const unsigned* fl = flags + (size_t)(t - 1) * NWG + tid;
            int guard = 0;
            while (__hip_atomic_load(fl, __ATOMIC_ACQUIRE, __HIP_MEMORY_SCOPE_AGENT) == 0u) {
                __builtin_amdgcn_s_sleep(1);
                if (++guard > 20000000) break;   // anti-hang bailout
            }
        }
        __syncthreads();

        // stage h_{t-1} into LDS (coherent agent-scope loads: bypass stale L1/L2)
        {
            const float* hsrc = h_buf + (size_t)(t & 1) * HD + tid * 4;
            float4 hv;
            hv.x = __hip_atomic_load(hsrc + 0, __ATOMIC_RELAXED, __HIP_MEMORY_SCOPE_AGENT);
            hv.y = __hip_atomic_load(hsrc + 1, __ATOMIC_RELAXED, __HIP_MEMORY_SCOPE_AGENT);
            hv.z = __hip_atomic_load(hsrc + 2, __ATOMIC_RELAXED, __HIP_MEMORY_SCOPE_AGENT);
            hv.w = __hip_atomic_load(hsrc + 3, __ATOMIC_RELAXED, __HIP_MEMORY_SCOPE_AGENT);
            h_s[tid] = hv;
        }
        __syncthreads();

        // matvec slice: 4 rows x 32 k per thread, W streamed from L2
        float a0 = 0.f, a1 = 0.f, a2 = 0.f, a3 = 0.f;
        const float4* hp = h_s + kq * 8;
        #pragma unroll
        for (int k4 = 0; k4 < 8; ++k4) {
            float4 h4 = hp[k4];
            float4 w0 = Wp[0 * 8 + k4]; a0 += w0.x*h4.x + w0.y*h4.y + w0.z*h4.z + w0.w*h4.w;
            float4 w1 = Wp[1 * 8 + k4]; a1 += w1.x*h4.x + w1.y*h4.y + w1.z*h4.z + w1.w*h4.w;
            float4 w2 = Wp[2 * 8 + k4]; a2 += w2.x*h4.x + w2.y*h4.y + w2.z*h4.z + w2.w*h4.w;
            float4 w3 = Wp[3 * 8 + k4]; a3 += w3.x*h4.x + w3.y*h4.y + w3.z*h4.z + w3.w*h4.w;
        }
        partial[rg * 4 + 0][kq] = a0;
        partial[rg * 4 + 1][kq] = a1;
        partial[rg * 4 + 2][kq] = a2;
        partial[rg * 4 + 3][kq] = a3;
        __syncthreads();

        if (tid < 32) {
            float s = gx;
            #pragma unroll
            for (int q = 0; q < 32; ++q) s += partial[tid][q];
            gv_s[tid] = s;
        }
        __syncthreads();

        if (tid < JPW) {
            float gi = gv_s[tid], gf = gv_s[8 + tid], gc = gv_s[16 + tid], go = gv_s[24 + tid];
            float si = 1.f / (1.f + expf(-gi));
            float sf = 1.f / (1.f + expf(-gf));
            float so = 1.f / (1.f + expf(-go));
            float c = sf * c_s[tid] + si * tanhf(gc);
            float h = so * tanhf(c);
            c_s[tid] = c;
            int j = g * JPW + tid;
            h_all[(size_t)t * HD + j] = h;   // consumed after kernel end
            __hip_atomic_store(h_buf + (size_t)((t + 1) & 1) * HD + j, h,
                               __ATOMIC_RELEASE, __HIP_MEMORY_SCOPE_AGENT);
        }
        __syncthreads();   // drains vmcnt: h stores complete before flag
        if (tid == 0)
            __hip_atomic_store(flags + (size_t)t * NWG + g, 1u,
                               __ATOMIC_RELEASE, __HIP_MEMORY_SCOPE_AGENT);
    }
}

// ---------------------------------------------------------------------------
// out[t][lab] = b_fc[lab] + sum_k h_all[t][k] * W_fc[lab][k]
__global__ __launch_bounds__(128) void fc_out(const float* __restrict__ h_all,
                                              const float* __restrict__ W_fc,
                                              const float* __restrict__ b_fc,
                                              float* __restrict__ out) {
    const int t = blockIdx.x;
    const int tid = threadIdx.x;
    __shared__ float4 h_s[256];
    const float4* hsrc = (const float4*)(h_all + (size_t)t * HD);
    h_s[tid] = hsrc[tid];
    h_s[tid + 128] = hsrc[tid + 128];
    __syncthreads();
    if (tid < NLAB) {
        float acc = b_fc[tid];
        const float4* wp = (const float4*)(W_fc + (size_t)tid * HD);
        #pragma unroll 8
        for (int k4 = 0; k4 < 256; ++k4) {
            float4 w = wp[k4];
            float4 h = h_s[k4];
            acc += w.x*h.x + w.y*h.y + w.z*h.z + w.w*h.w;
        }
        out[(size_t)t * NLAB + tid] = acc;
    }
}

// ---------------------------------------------------------------------------
extern "C" void kernel_launch(void* const* d_in, const int* in_sizes, int n_in,
                              void* d_out, int out_size, void* d_ws, size_t ws_size,
                              hipStream_t stream) {
    const float* x    = (const float*)d_in[0];
    const float* hi   = (const float*)d_in[1];
    const float* W_ih = (const float*)d_in[2];
    const float* W_hh = (const float*)d_in[3];
    const float* b_ih = (const float*)d_in[4];
    const float* b_hh = (const float*)d_in[5];
    const float* W_fc = (const float*)d_in[6];
    const float* b_fc = (const float*)d_in[7];
    float* out = (float*)d_out;

    char* ws = (char*)d_ws;
    float*    h_buf   = (float*)(ws + OFF_HBUF);
    unsigned* flags   = (unsigned*)(ws + OFF_FLAGS);
    float*    gates_x = (float*)(ws + OFF_GATES);
    float*    W_r2    = (float*)(ws + OFF_WR);
    float*    h_all   = (float*)(ws + OFF_HALL);

    // zero h_{-1} and all step flags (ws is re-poisoned 0xAA before every call)
    hipMemsetAsync(d_ws, 0, OFF_GATES, stream);

    prep_wr<<<4096, 256, 0, stream>>>(W_ih, W_hh, W_r2);

    dim3 gg(64, 8);   // 4096/64 r-tiles x 512/64 t-tiles
    gates_gemm<<<gg, 256, 0, stream>>>(x, hi, W_ih, b_ih, b_hh, gates_x);

    lstm_rec<<<NWG, 256, 0, stream>>>(gates_x, W_r2, h_all, h_buf, flags);

    fc_out<<<SEQL, 128, 0, stream>>>(h_all, W_fc, b_fc, out);
}

// Round 2
// 1586.190 us; speedup vs baseline: 4.1253x; 4.1253x over previous
//
#include <hip/hip_runtime.h>
#include <math.h>

// Problem constants
#define HD    1024      // hidden size
#define SEQL  512       // sequence length
#define NLAB  122       // labels
#define NWG   128       // workgroups in persistent recurrent kernel
#define JPW   8         // h-columns (j) per workgroup  (NWG*JPW == HD)

// Workspace layout (bytes). Total ≈ 27.3 MB.
#define OFF_MSG   ((size_t)0)          // h msg: 2*1024 u64 (tag<<32|h_bits)    = 16384 B
#define OFF_HALL  ((size_t)16384)      // h_all: 512*1024 fp32                  = 2097152 B
#define OFF_GATES ((size_t)2113536)    // gates_x: 512*4096 fp32                = 8388608 B
#define OFF_WR    ((size_t)10502144)   // W_r2: 4096*1024 fp32 (swizzled)       = 16777216 B
// end = 27279360

// ---------------------------------------------------------------------------
// Prep: W_r2[g][kq][row_local][kk] = W_ih[R][4096+k] + W_hh[R][k]
//   g in [0,128), kq in [0,32), row_local = gate*8+jj in [0,32), kk in [0,32)
//   R = gate*1024 + g*8 + jj,  k = kq*32 + kk
__global__ __launch_bounds__(256) void prep_wr(const float* __restrict__ W_ih,
                                               const float* __restrict__ W_hh,
                                               float* __restrict__ W_r2) {
    int idx4 = blockIdx.x * 256 + threadIdx.x;   // float4 index
    int e = idx4 * 4;                            // element index, < 4194304
    int g   = e >> 15;
    int rem = e & 32767;
    int kq  = rem >> 10;
    int row = (rem >> 5) & 31;
    int kk  = e & 31;
    int R = ((row >> 3) << 10) + (g << 3) + (row & 7);
    int k = (kq << 5) + kk;
    float4 wa = *(const float4*)(W_ih + (size_t)R * 5120 + 4096 + k);
    float4 wb = *(const float4*)(W_hh + (size_t)R * 1024 + k);
    float4 o;
    o.x = wa.x + wb.x; o.y = wa.y + wb.y; o.z = wa.z + wb.z; o.w = wa.w + wb.w;
    *(float4*)(W_r2 + e) = o;
}

// ---------------------------------------------------------------------------
// gates_x[t][r] = b_ih[r] + b_hh[r] + sum_{k<4096} feats[t][k] * W_ih[r][k]
// feats[t] = concat(x[t] (2048), hi[t] (2048)). 64x64 tile, BK=16, fp32 VALU.
__global__ __launch_bounds__(256) void gates_gemm(const float* __restrict__ x,
                                                  const float* __restrict__ hi,
                                                  const float* __restrict__ W_ih,
                                                  const float* __restrict__ b_ih,
                                                  const float* __restrict__ b_hh,
                                                  float* __restrict__ gates_x) {
    __shared__ float As[16][68];
    __shared__ float Bs[16][68];
    const int tid = threadIdx.x;
    const int r0 = blockIdx.x * 64;
    const int t0 = blockIdx.y * 64;
    const int tx = tid & 15, ty = tid >> 4;
    const int l   = tid & 63;
    const int kq4 = tid >> 6;

    float acc[4][4] = {};
    for (int kb = 0; kb < 4096; kb += 16) {
        int k = kb + kq4 * 4;
        const float* asrc = (k < 2048) ? (x  + (size_t)(t0 + l) * 2048 + k)
                                       : (hi + (size_t)(t0 + l) * 2048 + (k - 2048));
        float4 a4 = *(const float4*)asrc;
        float4 b4 = *(const float4*)(W_ih + (size_t)(r0 + l) * 5120 + k);
        __syncthreads();
        As[kq4 * 4 + 0][l] = a4.x; As[kq4 * 4 + 1][l] = a4.y;
        As[kq4 * 4 + 2][l] = a4.z; As[kq4 * 4 + 3][l] = a4.w;
        Bs[kq4 * 4 + 0][l] = b4.x; Bs[kq4 * 4 + 1][l] = b4.y;
        Bs[kq4 * 4 + 2][l] = b4.z; Bs[kq4 * 4 + 3][l] = b4.w;
        __syncthreads();
        #pragma unroll
        for (int kk = 0; kk < 16; ++kk) {
            float4 av = *(const float4*)&As[kk][ty * 4];
            float4 bv = *(const float4*)&Bs[kk][tx * 4];
            float a_[4] = {av.x, av.y, av.z, av.w};
            float b_[4] = {bv.x, bv.y, bv.z, bv.w};
            #pragma unroll
            for (int i = 0; i < 4; ++i)
                #pragma unroll
                for (int j = 0; j < 4; ++j)
                    acc[i][j] += a_[i] * b_[j];
        }
    }
    int r = r0 + tx * 4;
    float bias[4];
    #pragma unroll
    for (int j = 0; j < 4; ++j) bias[j] = b_ih[r + j] + b_hh[r + j];
    #pragma unroll
    for (int i = 0; i < 4; ++i) {
        float4 o;
        o.x = acc[i][0] + bias[0]; o.y = acc[i][1] + bias[1];
        o.z = acc[i][2] + bias[2]; o.w = acc[i][3] + bias[3];
        *(float4*)(gates_x + (size_t)(t0 + ty * 4 + i) * 4096 + r) = o;
    }
}

// ---------------------------------------------------------------------------
// Persistent recurrent kernel. 128 WGs x 256 threads, all co-resident.
// Weights live in VGPRs (float4 w[4][8] per thread = 128 VGPRs).
// h exchange: single-hop tag-in-word protocol. msg word = (tag s+1)<<32 | f32 h.
// RELAXED agent atomics only -> sc0/sc1 bypass loads/stores, NO buffer_inv
// cache wipes on the poll loop (that was R0's 12 us/step killer).
// Double-buffered by step parity (safe: WG at step s implies all WGs passed
// step s-1, so the tag s-1 entries being overwritten are dead).
__global__ __launch_bounds__(256, 1) void lstm_rec(const float* __restrict__ gates_x,
                                                   const float* __restrict__ W_r2,
                                                   float* __restrict__ h_all,
                                                   unsigned long long* h_msg) {
    const int g   = blockIdx.x;
    const int tid = threadIdx.x;
    const int kq  = tid >> 3;
    const int rg  = tid & 7;
    __shared__ float4 h_s[256];
    __shared__ float  partial[32][33];
    __shared__ float  gv_s[32];

    // load this thread's weight slice into registers (one-time, ~16.8 MB total)
    const float4* Wp = ((const float4*)W_r2) + ((size_t)(g * 32 + kq) * 32 + rg * 4) * 8;
    float4 w[4][8];
    #pragma unroll
    for (int r = 0; r < 4; ++r)
        #pragma unroll
        for (int k4 = 0; k4 < 8; ++k4)
            w[r][k4] = Wp[r * 8 + k4];

    float c = 0.f;               // cell state, meaningful in tid<8 lanes
    int budget = 2000000;        // anti-hang poll budget (per thread, whole kernel)

    for (int s = 0; s < SEQL; ++s) {
        // independent prefetch: this step's gates_x slice
        float gx = 0.f;
        if (tid < 32)
            gx = gates_x[(size_t)s * 4096 + ((tid >> 3) << 10) + (g << 3) + (tid & 7)];

        // poll h_{s-1}: thread tid owns msg words tid*4 .. tid*4+3
        {
            const unsigned long long* buf = h_msg + (size_t)(s & 1) * HD + tid * 4;
            const unsigned want = (unsigned)s;
            unsigned long long v0, v1, v2, v3;
            for (;;) {
                v0 = __hip_atomic_load(buf + 0, __ATOMIC_RELAXED, __HIP_MEMORY_SCOPE_AGENT);
                v1 = __hip_atomic_load(buf + 1, __ATOMIC_RELAXED, __HIP_MEMORY_SCOPE_AGENT);
                v2 = __hip_atomic_load(buf + 2, __ATOMIC_RELAXED, __HIP_MEMORY_SCOPE_AGENT);
                v3 = __hip_atomic_load(buf + 3, __ATOMIC_RELAXED, __HIP_MEMORY_SCOPE_AGENT);
                if ((unsigned)(v0 >> 32) == want && (unsigned)(v1 >> 32) == want &&
                    (unsigned)(v2 >> 32) == want && (unsigned)(v3 >> 32) == want) break;
                if (--budget < 0) break;
            }
            float4 hv;
            hv.x = __uint_as_float((unsigned)v0);
            hv.y = __uint_as_float((unsigned)v1);
            hv.z = __uint_as_float((unsigned)v2);
            hv.w = __uint_as_float((unsigned)v3);
            h_s[tid] = hv;
        }
        __syncthreads();

        // matvec slice: 4 rows x 32 k per thread, weights from registers
        float a0 = 0.f, a1 = 0.f, a2 = 0.f, a3 = 0.f;
        #pragma unroll
        for (int k4 = 0; k4 < 8; ++k4) {
            float4 h4 = h_s[kq * 8 + k4];
            a0 += w[0][k4].x*h4.x + w[0][k4].y*h4.y + w[0][k4].z*h4.z + w[0][k4].w*h4.w;
            a1 += w[1][k4].x*h4.x + w[1][k4].y*h4.y + w[1][k4].z*h4.z + w[1][k4].w*h4.w;
            a2 += w[2][k4].x*h4.x + w[2][k4].y*h4.y + w[2][k4].z*h4.z + w[2][k4].w*h4.w;
            a3 += w[3][k4].x*h4.x + w[3][k4].y*h4.y + w[3][k4].z*h4.z + w[3][k4].w*h4.w;
        }
        partial[rg * 4 + 0][kq] = a0;
        partial[rg * 4 + 1][kq] = a1;
        partial[rg * 4 + 2][kq] = a2;
        partial[rg * 4 + 3][kq] = a3;
        __syncthreads();

        if (tid < 32) {
            float sum = gx;
            #pragma unroll
            for (int q = 0; q < 32; ++q) sum += partial[tid][q];
            gv_s[tid] = sum;
        }
        __syncthreads();

        if (tid < JPW) {
            float gi = gv_s[tid], gf = gv_s[8 + tid], gc = gv_s[16 + tid], go = gv_s[24 + tid];
            float si = 1.f / (1.f + __expf(-gi));
            float sf = 1.f / (1.f + __expf(-gf));
            float so = 1.f / (1.f + __expf(-go));
            float tg = 2.f / (1.f + __expf(-2.f * gc)) - 1.f;   // tanh(gc)
            c = sf * c + si * tg;
            float th = 2.f / (1.f + __expf(-2.f * c)) - 1.f;    // tanh(c)
            float h = so * th;
            int j = g * JPW + tid;
            h_all[(size_t)s * HD + j] = h;   // consumed by fc_out after kernel end
            unsigned long long m = ((unsigned long long)(unsigned)(s + 1) << 32)
                                 | (unsigned long long)__float_as_uint(h);
            __hip_atomic_store(h_msg + (size_t)((s + 1) & 1) * HD + j, m,
                               __ATOMIC_RELAXED, __HIP_MEMORY_SCOPE_AGENT);
        }
        // no barrier needed here: gv_s isn't rewritten until after two
        // __syncthreads in the next iteration
    }
}

// ---------------------------------------------------------------------------
// out[t][lab] = b_fc[lab] + sum_k h_all[t][k] * W_fc[lab][k]
__global__ __launch_bounds__(128) void fc_out(const float* __restrict__ h_all,
                                              const float* __restrict__ W_fc,
                                              const float* __restrict__ b_fc,
                                              float* __restrict__ out) {
    const int t = blockIdx.x;
    const int tid = threadIdx.x;
    __shared__ float4 h_s[256];
    const float4* hsrc = (const float4*)(h_all + (size_t)t * HD);
    h_s[tid] = hsrc[tid];
    h_s[tid + 128] = hsrc[tid + 128];
    __syncthreads();
    if (tid < NLAB) {
        float acc = b_fc[tid];
        const float4* wp = (const float4*)(W_fc + (size_t)tid * HD);
        #pragma unroll 8
        for (int k4 = 0; k4 < 256; ++k4) {
            float4 w = wp[k4];
            float4 h = h_s[k4];
            acc += w.x*h.x + w.y*h.y + w.z*h.z + w.w*h.w;
        }
        out[(size_t)t * NLAB + tid] = acc;
    }
}

// ---------------------------------------------------------------------------
extern "C" void kernel_launch(void* const* d_in, const int* in_sizes, int n_in,
                              void* d_out, int out_size, void* d_ws, size_t ws_size,
                              hipStream_t stream) {
    const float* x    = (const float*)d_in[0];
    const float* hi   = (const float*)d_in[1];
    const float* W_ih = (const float*)d_in[2];
    const float* W_hh = (const float*)d_in[3];
    const float* b_ih = (const float*)d_in[4];
    const float* b_hh = (const float*)d_in[5];
    const float* W_fc = (const float*)d_in[6];
    const float* b_fc = (const float*)d_in[7];
    float* out = (float*)d_out;

    char* ws = (char*)d_ws;
    unsigned long long* h_msg = (unsigned long long*)(ws + OFF_MSG);
    float* h_all   = (float*)(ws + OFF_HALL);
    float* gates_x = (float*)(ws + OFF_GATES);
    float* W_r2    = (float*)(ws + OFF_WR);

    // zero the msg buffer: h_{-1}=0 with tag 0 (ws is re-poisoned 0xAA each call)
    hipMemsetAsync(d_ws, 0, 16384, stream);

    prep_wr<<<4096, 256, 0, stream>>>(W_ih, W_hh, W_r2);

    dim3 gg(64, 8);
    gates_gemm<<<gg, 256, 0, stream>>>(x, hi, W_ih, b_ih, b_hh, gates_x);

    lstm_rec<<<NWG, 256, 0, stream>>>(gates_x, W_r2, h_all, h_msg);

    fc_out<<<SEQL, 128, 0, stream>>>(h_all, W_fc, b_fc, out);
}